// Round 5
// baseline (586.766 us; speedup 1.0000x reference)
//
#include <hip/hip_runtime.h>
#include <math.h>

#define F_IN 512
#define NHEAD1 8
#define NC1 8
#define F1 64      // NHEAD1 * NC1
#define NC2 16
#define NEG_SLOPE 0.2f
#define BSHIFT 7                 // bucket = dst >> 7 (128 dsts per bucket)
#define PART_G 512               // partition blocks
#define BUILD_CAP 4608           // LDS staging capacity per bucket

static __device__ __forceinline__ float leaky(float v) {
    return v > 0.0f ? v : NEG_SLOPE * v;
}

// ---- GEMM1: h1[N,64] = x[N,512] @ W1[512,64]  + fused layer-1 logits ----
// A-tile stored transposed in LDS so both fragments read as ds_read_b128.
__global__ __launch_bounds__(256) void k_gemm1(const float* __restrict__ x,
                                               const float* __restrict__ W,
                                               const float* __restrict__ a1s,
                                               const float* __restrict__ a1d,
                                               float* __restrict__ h1,
                                               float* __restrict__ al1s,
                                               float* __restrict__ al1d, int N) {
    __shared__ float xs[32][68];   // [k][row]; 68 = 16B-aligned rows, <=2-way banks
    __shared__ float wsm[32][64];
    const int tid = threadIdx.x;
    const int tx = tid & 15, ty = tid >> 4;
    const int row0 = blockIdx.x * 64;
    // staging indices: thread loads row r, k-quadrant kq (8 consecutive k)
    const int r = tid & 63;
    const int kq = tid >> 6;       // 0..3
    float acc[4][4] = {};

    for (int k0 = 0; k0 < F_IN; k0 += 32) {
        {
            int gr = row0 + r;
            float4 v0 = make_float4(0.f, 0.f, 0.f, 0.f), v1 = v0;
            if (gr < N) {
                const float* p = x + (size_t)gr * F_IN + k0 + kq * 8;
                v0 = *(const float4*)p;
                v1 = *(const float4*)(p + 4);
            }
            xs[kq * 8 + 0][r] = v0.x; xs[kq * 8 + 1][r] = v0.y;
            xs[kq * 8 + 2][r] = v0.z; xs[kq * 8 + 3][r] = v0.w;
            xs[kq * 8 + 4][r] = v1.x; xs[kq * 8 + 5][r] = v1.y;
            xs[kq * 8 + 6][r] = v1.z; xs[kq * 8 + 7][r] = v1.w;
            int wr = tid >> 4;          // 0..15
            int wc = (tid & 15) * 4;    // 0..60
            #pragma unroll
            for (int rr = 0; rr < 32; rr += 16) {
                *(float4*)(&wsm[wr + rr][wc]) =
                    *(const float4*)(W + (size_t)(k0 + wr + rr) * F1 + wc);
            }
        }
        __syncthreads();
        #pragma unroll
        for (int k = 0; k < 32; ++k) {
            float4 a = *(const float4*)(&xs[k][ty * 4]);
            float4 b = *(const float4*)(&wsm[k][tx * 4]);
            acc[0][0] = fmaf(a.x, b.x, acc[0][0]); acc[0][1] = fmaf(a.x, b.y, acc[0][1]);
            acc[0][2] = fmaf(a.x, b.z, acc[0][2]); acc[0][3] = fmaf(a.x, b.w, acc[0][3]);
            acc[1][0] = fmaf(a.y, b.x, acc[1][0]); acc[1][1] = fmaf(a.y, b.y, acc[1][1]);
            acc[1][2] = fmaf(a.y, b.z, acc[1][2]); acc[1][3] = fmaf(a.y, b.w, acc[1][3]);
            acc[2][0] = fmaf(a.z, b.x, acc[2][0]); acc[2][1] = fmaf(a.z, b.y, acc[2][1]);
            acc[2][2] = fmaf(a.z, b.z, acc[2][2]); acc[2][3] = fmaf(a.z, b.w, acc[2][3]);
            acc[3][0] = fmaf(a.w, b.x, acc[3][0]); acc[3][1] = fmaf(a.w, b.y, acc[3][1]);
            acc[3][2] = fmaf(a.w, b.z, acc[3][2]); acc[3][3] = fmaf(a.w, b.w, acc[3][3]);
        }
        __syncthreads();
    }
    // store h1 + fused attention logits (thread: rows ty*4+i, cols tx*4..tx*4+3)
    const int h = tx >> 1;                    // head of this thread's 4 cols
    const float* as = a1s + h * 8 + (tx & 1) * 4;
    const float* ad = a1d + h * 8 + (tx & 1) * 4;
    float4 asv = *(const float4*)as;
    float4 adv = *(const float4*)ad;
    #pragma unroll
    for (int i = 0; i < 4; ++i) {
        int gr = row0 + ty * 4 + i;
        float ps = acc[i][0] * asv.x + acc[i][1] * asv.y
                 + acc[i][2] * asv.z + acc[i][3] * asv.w;
        float pd = acc[i][0] * adv.x + acc[i][1] * adv.y
                 + acc[i][2] * adv.z + acc[i][3] * adv.w;
        ps += __shfl_xor(ps, 1);
        pd += __shfl_xor(pd, 1);
        if (gr < N) {
            *(float4*)(h1 + (size_t)gr * F1 + tx * 4) =
                make_float4(acc[i][0], acc[i][1], acc[i][2], acc[i][3]);
            if ((tx & 1) == 0) {
                al1s[gr * 8 + h] = ps;
                al1d[gr * 8 + h] = pd;
            }
        }
    }
}

// ================= bucketed CSR build (no global atomics) =================
__global__ __launch_bounds__(256) void k_bcount(const int* __restrict__ ei,
                                                int* __restrict__ counts,
                                                int E, int NBUCK, int chunk) {
    __shared__ int cnt[1024];
    const int g = blockIdx.x, tid = threadIdx.x;
    for (int i = tid; i < NBUCK; i += 256) cnt[i] = 0;
    __syncthreads();
    int lo = g * chunk, hi = lo + chunk;
    if (hi > E) hi = E;
    for (int e = lo + tid; e < hi; e += 256)
        atomicAdd(&cnt[ei[E + e] >> BSHIFT], 1);
    __syncthreads();
    for (int k = tid; k < NBUCK; k += 256)
        counts[k * PART_G + g] = cnt[k];   // bucket-major for the scan
}

__global__ __launch_bounds__(256) void k_scan_block(const int* __restrict__ in,
                                                    int* __restrict__ out,
                                                    int* __restrict__ blocksum, int L) {
    __shared__ int sdata[256];
    int t = threadIdx.x;
    int i = blockIdx.x * 256 + t;
    int v = (i < L) ? in[i] : 0;
    sdata[t] = v;
    __syncthreads();
    for (int off = 1; off < 256; off <<= 1) {
        int add = (t >= off) ? sdata[t - off] : 0;
        __syncthreads();
        sdata[t] += add;
        __syncthreads();
    }
    if (i < L) out[i] = sdata[t] - v;
    if (t == 255) blocksum[blockIdx.x] = sdata[t];
}

__global__ void k_scan_carry(const int* __restrict__ blocksum,
                             int* __restrict__ blockoffset, int NB) {
    int lane = threadIdx.x;   // 64 threads, 1 block
    int carry = 0;
    for (int base = 0; base < NB; base += 64) {
        int i = base + lane;
        int v = (i < NB) ? blocksum[i] : 0;
        int x = v;
        #pragma unroll
        for (int off = 1; off < 64; off <<= 1) {
            int y = __shfl_up(x, off);
            if (lane >= off) x += y;
        }
        if (i < NB) blockoffset[i] = carry + x - v;
        carry += __shfl(x, 63);
    }
}

__global__ void k_scan_addg(int* __restrict__ out, const int* __restrict__ boff, int L) {
    int i = blockIdx.x * blockDim.x + threadIdx.x;
    if (i < L) out[i] += boff[i >> 8];
}

// scatter packed ((dst&127)<<20 | src) into bucket-major order, LDS cursors
__global__ __launch_bounds__(256) void k_bscatter(const int* __restrict__ ei,
                                                  const int* __restrict__ offs,
                                                  unsigned* __restrict__ packed,
                                                  int E, int NBUCK, int chunk) {
    __shared__ int cur[1024];
    const int g = blockIdx.x, tid = threadIdx.x;
    for (int k = tid; k < NBUCK; k += 256) cur[k] = offs[k * PART_G + g];
    __syncthreads();
    int lo = g * chunk, hi = lo + chunk;
    if (hi > E) hi = E;
    for (int e = lo + tid; e < hi; e += 256) {
        int src = ei[e], dst = ei[E + e];
        int pos = atomicAdd(&cur[dst >> BSHIFT], 1);
        packed[pos] = ((unsigned)(dst & 127) << 20) | (unsigned)src;
    }
}

// one block per bucket -> exact CSR (rowptr + esrc), coalesced output
__global__ __launch_bounds__(256) void k_bbuild(const unsigned* __restrict__ packed,
                                                const int* __restrict__ offs,
                                                int* __restrict__ rowptr,
                                                int* __restrict__ esrc,
                                                int E, int N, int NBUCK) {
    __shared__ int sdeg[128], sinc[128], scur[128];
    __shared__ int sbuf[BUILD_CAP];
    const int k = blockIdx.x, tid = threadIdx.x;
    const int s = offs[k * PART_G];
    const int e = (k + 1 < NBUCK) ? offs[(k + 1) * PART_G] : E;
    const int cnt = e - s;
    if (tid < 128) sdeg[tid] = 0;
    __syncthreads();
    for (int i = tid; i < cnt; i += 256)
        atomicAdd(&sdeg[packed[s + i] >> 20], 1);
    __syncthreads();
    if (tid < 128) sinc[tid] = sdeg[tid];
    __syncthreads();
    for (int off = 1; off < 128; off <<= 1) {
        int add = (tid < 128 && tid >= off) ? sinc[tid - off] : 0;
        __syncthreads();
        if (tid < 128) sinc[tid] += add;
        __syncthreads();
    }
    int nd = N - (k << BSHIFT);
    if (nd > 128) nd = 128;
    if (tid < nd) {
        int excl = sinc[tid] - sdeg[tid];
        rowptr[(k << BSHIFT) + tid] = s + excl;
        scur[tid] = excl;
    }
    if (k == 0 && tid == 0) rowptr[N] = E;
    __syncthreads();
    if (cnt <= BUILD_CAP) {
        for (int i = tid; i < cnt; i += 256) {
            unsigned p = packed[s + i];
            int pos = atomicAdd(&scur[p >> 20], 1);
            sbuf[pos] = (int)(p & 0xFFFFFu);
        }
        __syncthreads();
        for (int i = tid; i < cnt; i += 256) esrc[s + i] = sbuf[i];
    } else {
        for (int i = tid; i < cnt; i += 256) {
            unsigned p = packed[s + i];
            int pos = atomicAdd(&scur[p >> 20], 1);
            esrc[s + pos] = (int)(p & 0xFFFFFu);
        }
    }
}

// ---- layer-1 aggregation (no-max softmax), fused ELU+b1 + 64x16 GEMM +
// ---- layer-2 logits. Wave per node. fp32 throughout.
__global__ __launch_bounds__(256) void k_agg1(
    const float* __restrict__ h1, const float* __restrict__ al1s,
    const float* __restrict__ al1d, const int* __restrict__ rowptr,
    const int* __restrict__ esrc, const float* __restrict__ b1,
    const float* __restrict__ W2, const float* __restrict__ a2s,
    const float* __restrict__ a2d, float* __restrict__ h2,
    float* __restrict__ al2s, float* __restrict__ al2d, int N) {
    const int lane = threadIdx.x & 63;
    const int wv = threadIdx.x >> 6;
    const int n = blockIdx.x * 4 + wv;
    const int h = lane >> 3;                 // layer-1 head
    const int q = lane >> 4, c = lane & 15;  // fused-gemm quarter/col
    if (n >= N) return;

    float w2reg[16];
    #pragma unroll
    for (int j = 0; j < 16; ++j) w2reg[j] = W2[(q * 16 + j) * NC2 + c];
    const float b1l = b1[lane];
    const float a2sc = a2s[c], a2dc = a2d[c];

    const float aldh = al1d[n * 8 + h];
    // self-loop (m == 0 globally: logits are small, exp cannot overflow)
    float w0 = __expf(leaky(al1s[n * 8 + h] + aldh));
    float s = w0;
    float acc = w0 * h1[(size_t)n * F1 + lane];

    const int start = rowptr[n], end = rowptr[n + 1];
    for (int base = start; base < end; base += 64) {
        int cntv = end - base;
        if (cntv > 64) cntv = 64;
        int msrc = (lane < cntv) ? esrc[base + lane] : 0;
        for (int j = 0; j < cntv; ++j) {
            int src = __shfl(msrc, j);
            float w = __expf(leaky(al1s[src * 8 + h] + aldh));
            float hv = h1[(size_t)src * F1 + lane];
            s += w;
            acc = fmaf(w, hv, acc);
        }
    }
    // ELU(out + b1)
    float v = acc / s + b1l;
    v = v > 0.0f ? v : expm1f(v);
    // fused 64x16 gemm: h2[n][c] = sum_ch v_ch * W2[ch][c]
    float part = 0.f;
    #pragma unroll
    for (int j = 0; j < 16; ++j)
        part += __shfl(v, q * 16 + j) * w2reg[j];
    part += __shfl_xor(part, 16);
    part += __shfl_xor(part, 32);
    // layer-2 logits
    float ts = part * a2sc, td = part * a2dc;
    #pragma unroll
    for (int off = 1; off < 16; off <<= 1) {
        ts += __shfl_xor(ts, off);
        td += __shfl_xor(td, off);
    }
    if (lane < 16) h2[(size_t)n * NC2 + c] = part;
    if (lane == 0) { al2s[n] = ts; al2d[n] = td; }
}

// ---- layer-2 aggregation (no-max softmax) + bias + log-softmax ----
__global__ __launch_bounds__(256) void k_agg2(
    const float* __restrict__ h2, const float* __restrict__ al2s,
    const float* __restrict__ al2d, const int* __restrict__ rowptr,
    const int* __restrict__ esrc, const float* __restrict__ b2,
    float* __restrict__ out, int N) {
    const int lane = threadIdx.x & 63;
    const int wv = threadIdx.x >> 6;
    const int n = blockIdx.x * 4 + wv;
    const int q = lane >> 4, c = lane & 15;
    if (n >= N) return;
    const float b2c = b2[c];
    const float ald = al2d[n];
    float s, acc;
    if (q == 0) {   // self-loop handled by quarter 0
        float w0 = __expf(leaky(al2s[n] + ald));
        s = w0;
        acc = w0 * h2[(size_t)n * NC2 + c];
    } else {
        s = 0.f; acc = 0.f;
    }
    const int start = rowptr[n], end = rowptr[n + 1];
    for (int k = start + q; k < end; k += 4) {
        int src = esrc[k];
        float w = __expf(leaky(al2s[src] + ald));
        float hv = h2[(size_t)src * NC2 + c];
        s += w;
        acc = fmaf(w, hv, acc);
    }
    // merge quarters
    s += __shfl_xor(s, 16);   acc += __shfl_xor(acc, 16);
    s += __shfl_xor(s, 32);   acc += __shfl_xor(acc, 32);
    float v = acc / s + b2c;
    // log-softmax over 16 classes
    float mm = v;
    #pragma unroll
    for (int off = 1; off < 16; off <<= 1) mm = fmaxf(mm, __shfl_xor(mm, off));
    float se = __expf(v - mm);
    #pragma unroll
    for (int off = 1; off < 16; off <<= 1) se += __shfl_xor(se, off);
    if (lane < 16) out[(size_t)n * NC2 + c] = v - (logf(se) + mm);
}

extern "C" void kernel_launch(void* const* d_in, const int* in_sizes, int n_in,
                              void* d_out, int out_size, void* d_ws, size_t ws_size,
                              hipStream_t stream) {
    const float* x      = (const float*)d_in[0];
    const int*   ei     = (const int*)d_in[1];
    const float* W1     = (const float*)d_in[2];
    const float* a1_src = (const float*)d_in[3];
    const float* a1_dst = (const float*)d_in[4];
    const float* b1     = (const float*)d_in[5];
    const float* W2     = (const float*)d_in[6];
    const float* a2_src = (const float*)d_in[7];
    const float* a2_dst = (const float*)d_in[8];
    const float* b2     = (const float*)d_in[9];
    float* out = (float*)d_out;

    const int N = in_sizes[0] / F_IN;
    const int E = in_sizes[1] / 2;
    const int NH = N * NHEAD1;
    const int NBUCK = (N + 127) >> BSHIFT;
    const int L = NBUCK * PART_G;
    const int NB = (L + 255) / 256;
    const int chunk = (E + PART_G - 1) / PART_G;

    char* base = (char*)d_ws;
    size_t off = 0;
    auto alloc = [&](size_t bytes, size_t align) -> void* {
        off = (off + align - 1) & ~(align - 1);
        void* p = base + off; off += bytes; return p;
    };
    float* h1   = (float*)alloc((size_t)N * F1 * 4, 16);
    float* al1s = (float*)alloc((size_t)NH * 4, 16);
    float* al1d = (float*)alloc((size_t)NH * 4, 16);
    float* h2   = (float*)alloc((size_t)N * NC2 * 4, 16);
    float* al2s = (float*)alloc((size_t)N * 4, 16);
    float* al2d = (float*)alloc((size_t)N * 4, 16);
    int* rowptr = (int*)alloc((size_t)(N + 1) * 4, 16);
    int* esrc   = (int*)alloc((size_t)E * 4, 16);
    // CSR temps overlay h1 (h1 written AFTER k_bbuild completes; same stream)
    char* tbase = (char*)h1;
    unsigned* packed = (unsigned*)tbase;                    // E * 4
    int* counts   = (int*)(tbase + (size_t)E * 4);          // L * 4
    int* offs     = counts + L;                             // L * 4
    int* blocksum = offs + L;                               // NB * 4
    int* boffset  = blocksum + NB;                          // NB * 4

    const int B = 256;
    auto blocks = [](long long cnt, int b) { return (int)((cnt + b - 1) / b); };

    // ---- CSR build ----
    k_bcount<<<PART_G, 256, 0, stream>>>(ei, counts, E, NBUCK, chunk);
    k_scan_block<<<NB, 256, 0, stream>>>(counts, offs, blocksum, L);
    k_scan_carry<<<1, 64, 0, stream>>>(blocksum, boffset, NB);
    k_scan_addg<<<blocks(L, B), B, 0, stream>>>(offs, boffset, L);
    k_bscatter<<<PART_G, 256, 0, stream>>>(ei, offs, packed, E, NBUCK, chunk);
    k_bbuild<<<NBUCK, 256, 0, stream>>>(packed, offs, rowptr, esrc, E, N, NBUCK);

    // ---- layer 1 (gemm + fused logits) ----
    k_gemm1<<<dim3((N + 63) / 64), dim3(256), 0, stream>>>(x, W1, a1_src, a1_dst,
                                                           h1, al1s, al1d, N);
    k_agg1<<<blocks(N, 4), 256, 0, stream>>>(h1, al1s, al1d, rowptr, esrc,
                                             b1, W2, a2_src, a2_dst,
                                             h2, al2s, al2d, N);
    // ---- layer 2 + log-softmax ----
    k_agg2<<<blocks(N, 4), 256, 0, stream>>>(h2, al2s, al2d, rowptr, esrc, b2, out, N);
}

// Round 6
// 566.225 us; speedup vs baseline: 1.0363x; 1.0363x over previous
//
#include <hip/hip_runtime.h>
#include <math.h>

#define F_IN 512
#define NHEAD1 8
#define NC1 8
#define F1 64      // NHEAD1 * NC1
#define NC2 16
#define NEG_SLOPE 0.2f
#define BSHIFT 7                 // bucket = dst >> 7 (128 dsts per bucket)
#define PART_G 512               // partition blocks
#define BUILD_CAP 4608           // LDS staging capacity per bucket

static __device__ __forceinline__ float leaky(float v) {
    return v > 0.0f ? v : NEG_SLOPE * v;
}

// ---- GEMM1: h1[N,64] = x[N,512] @ W1[512,64]  + fused layer-1 logits ----
__global__ __launch_bounds__(256) void k_gemm1(const float* __restrict__ x,
                                               const float* __restrict__ W,
                                               const float* __restrict__ a1s,
                                               const float* __restrict__ a1d,
                                               float* __restrict__ h1,
                                               float* __restrict__ al1s,
                                               float* __restrict__ al1d, int N) {
    __shared__ float xs[32][68];   // [k][row]; 68 keeps 16B alignment, <=2-way banks
    __shared__ float wsm[32][64];
    const int tid = threadIdx.x;
    const int tx = tid & 15, ty = tid >> 4;
    const int row0 = blockIdx.x * 64;
    const int r = tid & 63;
    const int kq = tid >> 6;       // 0..3
    float acc[4][4] = {};

    for (int k0 = 0; k0 < F_IN; k0 += 32) {
        {
            int gr = row0 + r;
            float4 v0 = make_float4(0.f, 0.f, 0.f, 0.f), v1 = v0;
            if (gr < N) {
                const float* p = x + (size_t)gr * F_IN + k0 + kq * 8;
                v0 = *(const float4*)p;
                v1 = *(const float4*)(p + 4);
            }
            xs[kq * 8 + 0][r] = v0.x; xs[kq * 8 + 1][r] = v0.y;
            xs[kq * 8 + 2][r] = v0.z; xs[kq * 8 + 3][r] = v0.w;
            xs[kq * 8 + 4][r] = v1.x; xs[kq * 8 + 5][r] = v1.y;
            xs[kq * 8 + 6][r] = v1.z; xs[kq * 8 + 7][r] = v1.w;
            int wr = tid >> 4;
            int wc = (tid & 15) * 4;
            #pragma unroll
            for (int rr = 0; rr < 32; rr += 16) {
                *(float4*)(&wsm[wr + rr][wc]) =
                    *(const float4*)(W + (size_t)(k0 + wr + rr) * F1 + wc);
            }
        }
        __syncthreads();
        #pragma unroll
        for (int k = 0; k < 32; ++k) {
            float4 a = *(const float4*)(&xs[k][ty * 4]);
            float4 b = *(const float4*)(&wsm[k][tx * 4]);
            acc[0][0] = fmaf(a.x, b.x, acc[0][0]); acc[0][1] = fmaf(a.x, b.y, acc[0][1]);
            acc[0][2] = fmaf(a.x, b.z, acc[0][2]); acc[0][3] = fmaf(a.x, b.w, acc[0][3]);
            acc[1][0] = fmaf(a.y, b.x, acc[1][0]); acc[1][1] = fmaf(a.y, b.y, acc[1][1]);
            acc[1][2] = fmaf(a.y, b.z, acc[1][2]); acc[1][3] = fmaf(a.y, b.w, acc[1][3]);
            acc[2][0] = fmaf(a.z, b.x, acc[2][0]); acc[2][1] = fmaf(a.z, b.y, acc[2][1]);
            acc[2][2] = fmaf(a.z, b.z, acc[2][2]); acc[2][3] = fmaf(a.z, b.w, acc[2][3]);
            acc[3][0] = fmaf(a.w, b.x, acc[3][0]); acc[3][1] = fmaf(a.w, b.y, acc[3][1]);
            acc[3][2] = fmaf(a.w, b.z, acc[3][2]); acc[3][3] = fmaf(a.w, b.w, acc[3][3]);
        }
        __syncthreads();
    }
    const int h = tx >> 1;
    const float* as = a1s + h * 8 + (tx & 1) * 4;
    const float* ad = a1d + h * 8 + (tx & 1) * 4;
    float4 asv = *(const float4*)as;
    float4 adv = *(const float4*)ad;
    #pragma unroll
    for (int i = 0; i < 4; ++i) {
        int gr = row0 + ty * 4 + i;
        float ps = acc[i][0] * asv.x + acc[i][1] * asv.y
                 + acc[i][2] * asv.z + acc[i][3] * asv.w;
        float pd = acc[i][0] * adv.x + acc[i][1] * adv.y
                 + acc[i][2] * adv.z + acc[i][3] * adv.w;
        ps += __shfl_xor(ps, 1);
        pd += __shfl_xor(pd, 1);
        if (gr < N) {
            *(float4*)(h1 + (size_t)gr * F1 + tx * 4) =
                make_float4(acc[i][0], acc[i][1], acc[i][2], acc[i][3]);
            if ((tx & 1) == 0) {
                al1s[gr * 8 + h] = ps;
                al1d[gr * 8 + h] = pd;
            }
        }
    }
}

// ================= bucketed CSR build (no global atomics) =================
__global__ __launch_bounds__(256) void k_bcount(const int* __restrict__ ei,
                                                int* __restrict__ counts,
                                                int E, int NBUCK, int chunk) {
    __shared__ int cnt[1024];
    const int g = blockIdx.x, tid = threadIdx.x;
    for (int i = tid; i < NBUCK; i += 256) cnt[i] = 0;
    __syncthreads();
    int lo = g * chunk, hi = lo + chunk;
    if (hi > E) hi = E;
    for (int e = lo + tid; e < hi; e += 256)
        atomicAdd(&cnt[ei[E + e] >> BSHIFT], 1);
    __syncthreads();
    for (int k = tid; k < NBUCK; k += 256)
        counts[k * PART_G + g] = cnt[k];   // bucket-major for the scan
}

__global__ __launch_bounds__(256) void k_scan_block(const int* __restrict__ in,
                                                    int* __restrict__ out,
                                                    int* __restrict__ blocksum, int L) {
    __shared__ int sdata[256];
    int t = threadIdx.x;
    int i = blockIdx.x * 256 + t;
    int v = (i < L) ? in[i] : 0;
    sdata[t] = v;
    __syncthreads();
    for (int off = 1; off < 256; off <<= 1) {
        int add = (t >= off) ? sdata[t - off] : 0;
        __syncthreads();
        sdata[t] += add;
        __syncthreads();
    }
    if (i < L) out[i] = sdata[t] - v;
    if (t == 255) blocksum[blockIdx.x] = sdata[t];
}

__global__ void k_scan_carry(const int* __restrict__ blocksum,
                             int* __restrict__ blockoffset, int NB) {
    int lane = threadIdx.x;   // 64 threads, 1 block
    int carry = 0;
    for (int base = 0; base < NB; base += 64) {
        int i = base + lane;
        int v = (i < NB) ? blocksum[i] : 0;
        int x = v;
        #pragma unroll
        for (int off = 1; off < 64; off <<= 1) {
            int y = __shfl_up(x, off);
            if (lane >= off) x += y;
        }
        if (i < NB) blockoffset[i] = carry + x - v;
        carry += __shfl(x, 63);
    }
}

// scatter packed ((dst&127)<<20 | src); block offsets folded in on the fly
__global__ __launch_bounds__(256) void k_bscatter(const int* __restrict__ ei,
                                                  const int* __restrict__ offs,
                                                  const int* __restrict__ boff,
                                                  unsigned* __restrict__ packed,
                                                  int E, int NBUCK, int chunk) {
    __shared__ int cur[1024];
    const int g = blockIdx.x, tid = threadIdx.x;
    for (int k = tid; k < NBUCK; k += 256) {
        int idx = k * PART_G + g;
        cur[k] = offs[idx] + boff[idx >> 8];
    }
    __syncthreads();
    int lo = g * chunk, hi = lo + chunk;
    if (hi > E) hi = E;
    for (int e = lo + tid; e < hi; e += 256) {
        int src = ei[e], dst = ei[E + e];
        int pos = atomicAdd(&cur[dst >> BSHIFT], 1);
        packed[pos] = ((unsigned)(dst & 127) << 20) | (unsigned)src;
    }
}

// one block per bucket -> exact CSR (rowptr + esrc), coalesced output
__global__ __launch_bounds__(256) void k_bbuild(const unsigned* __restrict__ packed,
                                                const int* __restrict__ offs,
                                                const int* __restrict__ boff,
                                                int* __restrict__ rowptr,
                                                int* __restrict__ esrc,
                                                int E, int N, int NBUCK) {
    __shared__ int sdeg[128], sinc[128], scur[128];
    __shared__ int sbuf[BUILD_CAP];
    const int k = blockIdx.x, tid = threadIdx.x;
    const int i0 = k * PART_G;
    const int s = offs[i0] + boff[i0 >> 8];
    int e;
    if (k + 1 < NBUCK) {
        int i1 = (k + 1) * PART_G;
        e = offs[i1] + boff[i1 >> 8];
    } else e = E;
    const int cnt = e - s;
    if (tid < 128) sdeg[tid] = 0;
    __syncthreads();
    for (int i = tid; i < cnt; i += 256)
        atomicAdd(&sdeg[packed[s + i] >> 20], 1);
    __syncthreads();
    if (tid < 128) sinc[tid] = sdeg[tid];
    __syncthreads();
    for (int off = 1; off < 128; off <<= 1) {
        int add = (tid < 128 && tid >= off) ? sinc[tid - off] : 0;
        __syncthreads();
        if (tid < 128) sinc[tid] += add;
        __syncthreads();
    }
    int nd = N - (k << BSHIFT);
    if (nd > 128) nd = 128;
    if (tid < nd) {
        int excl = sinc[tid] - sdeg[tid];
        rowptr[(k << BSHIFT) + tid] = s + excl;
        scur[tid] = excl;
    }
    if (k == 0 && tid == 0) rowptr[N] = E;
    __syncthreads();
    if (cnt <= BUILD_CAP) {
        for (int i = tid; i < cnt; i += 256) {
            unsigned p = packed[s + i];
            int pos = atomicAdd(&scur[p >> 20], 1);
            sbuf[pos] = (int)(p & 0xFFFFFu);
        }
        __syncthreads();
        for (int i = tid; i < cnt; i += 256) esrc[s + i] = sbuf[i];
    } else {
        for (int i = tid; i < cnt; i += 256) {
            unsigned p = packed[s + i];
            int pos = atomicAdd(&scur[p >> 20], 1);
            esrc[s + pos] = (int)(p & 0xFFFFFu);
        }
    }
}

// ---- layer-1 aggregation: wave/node, 4 edges in parallel (16 lanes/edge,
// ---- float4 gather), fused ELU+b1 + 64x16 GEMM + layer-2 logits. fp32.
__global__ __launch_bounds__(256) void k_agg1(
    const float* __restrict__ h1, const float* __restrict__ al1s,
    const float* __restrict__ al1d, const int* __restrict__ rowptr,
    const int* __restrict__ esrc, const float* __restrict__ b1,
    const float* __restrict__ W2, const float* __restrict__ a2s,
    const float* __restrict__ a2d, float* __restrict__ h2,
    float* __restrict__ al2s, float* __restrict__ al2d, int N) {
    const int lane = threadIdx.x & 63;
    const int wv = threadIdx.x >> 6;
    const int n = blockIdx.x * 4 + wv;
    if (n >= N) return;
    const int sub = lane >> 4;        // edge slot 0..3
    const int t = lane & 15;          // channels 4t..4t+3
    const int h = t >> 1;             // layer-1 head of these channels

    float4 w2r[4];
    #pragma unroll
    for (int j = 0; j < 4; ++j)
        w2r[j] = *(const float4*)(W2 + (4 * t + j) * NC2 + 4 * sub);
    const float4 b1v  = *(const float4*)(b1 + 4 * t);
    const float4 a2sv = *(const float4*)(a2s + 4 * sub);
    const float4 a2dv = *(const float4*)(a2d + 4 * sub);

    const float aldh = al1d[n * 8 + h];
    float s = 0.f, acc0 = 0.f, acc1 = 0.f, acc2 = 0.f, acc3 = 0.f;
    if (sub == 0) {   // self-loop
        float w0 = __expf(leaky(al1s[n * 8 + h] + aldh));
        float4 u = *(const float4*)(h1 + (size_t)n * F1 + t * 4);
        s = w0;
        acc0 = w0 * u.x; acc1 = w0 * u.y; acc2 = w0 * u.z; acc3 = w0 * u.w;
    }
    const int start = rowptr[n], end = rowptr[n + 1];
    for (int base = start; base < end; base += 64) {
        int cnt = end - base;
        if (cnt > 64) cnt = 64;
        int msrc = (lane < cnt) ? esrc[base + lane] : 0;
        for (int j4 = 0; j4 < cnt; j4 += 4) {
            int idx = j4 + sub;
            int src = __shfl(msrc, idx);
            float w = (idx < cnt) ? __expf(leaky(al1s[src * 8 + h] + aldh)) : 0.f;
            float4 u = *(const float4*)(h1 + (size_t)src * F1 + t * 4);
            s += w;
            acc0 = fmaf(w, u.x, acc0);
            acc1 = fmaf(w, u.y, acc1);
            acc2 = fmaf(w, u.z, acc2);
            acc3 = fmaf(w, u.w, acc3);
        }
    }
    // merge the 4 edge slots
    #pragma unroll
    for (int off = 16; off < 64; off <<= 1) {
        s    += __shfl_xor(s, off);
        acc0 += __shfl_xor(acc0, off);
        acc1 += __shfl_xor(acc1, off);
        acc2 += __shfl_xor(acc2, off);
        acc3 += __shfl_xor(acc3, off);
    }
    float rs = 1.0f / s;
    float v0 = acc0 * rs + b1v.x; v0 = v0 > 0.f ? v0 : expm1f(v0);
    float v1 = acc1 * rs + b1v.y; v1 = v1 > 0.f ? v1 : expm1f(v1);
    float v2 = acc2 * rs + b1v.z; v2 = v2 > 0.f ? v2 : expm1f(v2);
    float v3 = acc3 * rs + b1v.w; v3 = v3 > 0.f ? v3 : expm1f(v3);
    // fused gemm: cols 4sub..4sub+3, partial over channels 4t..4t+3
    float p0 = v0 * w2r[0].x + v1 * w2r[1].x + v2 * w2r[2].x + v3 * w2r[3].x;
    float p1 = v0 * w2r[0].y + v1 * w2r[1].y + v2 * w2r[2].y + v3 * w2r[3].y;
    float p2 = v0 * w2r[0].z + v1 * w2r[1].z + v2 * w2r[2].z + v3 * w2r[3].z;
    float p3 = v0 * w2r[0].w + v1 * w2r[1].w + v2 * w2r[2].w + v3 * w2r[3].w;
    #pragma unroll
    for (int off = 1; off < 16; off <<= 1) {
        p0 += __shfl_xor(p0, off);
        p1 += __shfl_xor(p1, off);
        p2 += __shfl_xor(p2, off);
        p3 += __shfl_xor(p3, off);
    }
    // layer-2 logits
    float ts = p0 * a2sv.x + p1 * a2sv.y + p2 * a2sv.z + p3 * a2sv.w;
    float td = p0 * a2dv.x + p1 * a2dv.y + p2 * a2dv.z + p3 * a2dv.w;
    ts += __shfl_xor(ts, 16); ts += __shfl_xor(ts, 32);
    td += __shfl_xor(td, 16); td += __shfl_xor(td, 32);
    if (t == 0)
        *(float4*)(h2 + (size_t)n * NC2 + sub * 4) = make_float4(p0, p1, p2, p3);
    if (lane == 0) { al2s[n] = ts; al2d[n] = td; }
}

// ---- layer-2 aggregation: 8 edges in parallel (8 lanes/edge, float2),
// ---- + bias + log-softmax, writes d_out. fp32.
__global__ __launch_bounds__(256) void k_agg2(
    const float* __restrict__ h2, const float* __restrict__ al2s,
    const float* __restrict__ al2d, const int* __restrict__ rowptr,
    const int* __restrict__ esrc, const float* __restrict__ b2,
    float* __restrict__ out, int N) {
    const int lane = threadIdx.x & 63;
    const int wv = threadIdx.x >> 6;
    const int n = blockIdx.x * 4 + wv;
    if (n >= N) return;
    const int sub = lane >> 3;   // edge slot 0..7
    const int t = lane & 7;      // channels 2t, 2t+1
    const float ald = al2d[n];
    float s = 0.f, a0 = 0.f, a1 = 0.f;
    if (sub == 0) {   // self-loop
        float w0 = __expf(leaky(al2s[n] + ald));
        float2 u = *(const float2*)(h2 + (size_t)n * NC2 + t * 2);
        s = w0;
        a0 = w0 * u.x;
        a1 = w0 * u.y;
    }
    const int start = rowptr[n], end = rowptr[n + 1];
    for (int base = start; base < end; base += 64) {
        int cnt = end - base;
        if (cnt > 64) cnt = 64;
        int msrc = (lane < cnt) ? esrc[base + lane] : 0;
        for (int j8 = 0; j8 < cnt; j8 += 8) {
            int idx = j8 + sub;
            int src = __shfl(msrc, idx);
            float w = (idx < cnt) ? __expf(leaky(al2s[src] + ald)) : 0.f;
            float2 u = *(const float2*)(h2 + (size_t)src * NC2 + t * 2);
            s += w;
            a0 = fmaf(w, u.x, a0);
            a1 = fmaf(w, u.y, a1);
        }
    }
    #pragma unroll
    for (int off = 8; off < 64; off <<= 1) {
        s  += __shfl_xor(s, off);
        a0 += __shfl_xor(a0, off);
        a1 += __shfl_xor(a1, off);
    }
    float rs = 1.0f / s;
    float2 b2v = *(const float2*)(b2 + 2 * t);
    float v0 = a0 * rs + b2v.x;
    float v1 = a1 * rs + b2v.y;
    float mm = fmaxf(v0, v1);
    #pragma unroll
    for (int off = 1; off < 8; off <<= 1) mm = fmaxf(mm, __shfl_xor(mm, off));
    float se = __expf(v0 - mm) + __expf(v1 - mm);
    #pragma unroll
    for (int off = 1; off < 8; off <<= 1) se += __shfl_xor(se, off);
    float l = logf(se) + mm;
    if (sub == 0)
        *(float2*)(out + (size_t)n * NC2 + 2 * t) = make_float2(v0 - l, v1 - l);
}

extern "C" void kernel_launch(void* const* d_in, const int* in_sizes, int n_in,
                              void* d_out, int out_size, void* d_ws, size_t ws_size,
                              hipStream_t stream) {
    const float* x      = (const float*)d_in[0];
    const int*   ei     = (const int*)d_in[1];
    const float* W1     = (const float*)d_in[2];
    const float* a1_src = (const float*)d_in[3];
    const float* a1_dst = (const float*)d_in[4];
    const float* b1     = (const float*)d_in[5];
    const float* W2     = (const float*)d_in[6];
    const float* a2_src = (const float*)d_in[7];
    const float* a2_dst = (const float*)d_in[8];
    const float* b2     = (const float*)d_in[9];
    float* out = (float*)d_out;

    const int N = in_sizes[0] / F_IN;
    const int E = in_sizes[1] / 2;
    const int NH = N * NHEAD1;
    const int NBUCK = (N + 127) >> BSHIFT;
    const int L = NBUCK * PART_G;
    const int NB = (L + 255) / 256;
    const int chunk = (E + PART_G - 1) / PART_G;

    char* base = (char*)d_ws;
    size_t off = 0;
    auto alloc = [&](size_t bytes, size_t align) -> void* {
        off = (off + align - 1) & ~(align - 1);
        void* p = base + off; off += bytes; return p;
    };
    float* h1   = (float*)alloc((size_t)N * F1 * 4, 16);
    float* al1s = (float*)alloc((size_t)NH * 4, 16);
    float* al1d = (float*)alloc((size_t)NH * 4, 16);
    float* h2   = (float*)alloc((size_t)N * NC2 * 4, 16);
    float* al2s = (float*)alloc((size_t)N * 4, 16);
    float* al2d = (float*)alloc((size_t)N * 4, 16);
    int* rowptr = (int*)alloc((size_t)(N + 1) * 4, 16);
    int* esrc   = (int*)alloc((size_t)E * 4, 16);
    // CSR temps overlay h1 (h1 written AFTER k_bbuild completes; same stream)
    char* tbase = (char*)h1;
    unsigned* packed = (unsigned*)tbase;                    // E * 4
    int* counts   = (int*)(tbase + (size_t)E * 4);          // L * 4
    int* offs     = counts + L;                             // L * 4
    int* blocksum = offs + L;                               // NB * 4
    int* boffset  = blocksum + NB;                          // NB * 4

    const int B = 256;
    auto blocks = [](long long cnt, int b) { return (int)((cnt + b - 1) / b); };

    // ---- CSR build ----
    k_bcount<<<PART_G, 256, 0, stream>>>(ei, counts, E, NBUCK, chunk);
    k_scan_block<<<NB, 256, 0, stream>>>(counts, offs, blocksum, L);
    k_scan_carry<<<1, 64, 0, stream>>>(blocksum, boffset, NB);
    k_bscatter<<<PART_G, 256, 0, stream>>>(ei, offs, boffset, packed, E, NBUCK, chunk);
    k_bbuild<<<NBUCK, 256, 0, stream>>>(packed, offs, boffset, rowptr, esrc, E, N, NBUCK);

    // ---- layer 1 (gemm + fused logits) ----
    k_gemm1<<<dim3((N + 63) / 64), dim3(256), 0, stream>>>(x, W1, a1_src, a1_dst,
                                                           h1, al1s, al1d, N);
    k_agg1<<<blocks(N, 4), 256, 0, stream>>>(h1, al1s, al1d, rowptr, esrc,
                                             b1, W2, a2_src, a2_dst,
                                             h2, al2s, al2d, N);
    // ---- layer 2 + log-softmax ----
    k_agg2<<<blocks(N, 4), 256, 0, stream>>>(h2, al2s, al2d, rowptr, esrc, b2, out, N);
}